// Round 9
// baseline (64.090 us; speedup 1.0000x reference)
//
#include <hip/hip_runtime.h>

#define S_LEN 4096
#define DIM   64
#define HALF  50
#define RB    128           // query rows per block
#define WQ    16            // query rows per wave (8 waves)
#define THREADS 512
#define KCAP  256           // staged V keys: kstart = r0-64 (32-aligned), span <= 242
#define NT    5             // max 32-key tiles per wave
#define SCALE 0.125f

typedef __attribute__((ext_vector_type(8))) short bf16x8;
typedef __attribute__((ext_vector_type(4))) float f32x4;

__device__ __forceinline__ unsigned int bf16_rne(float f) {
    unsigned int u = __float_as_uint(f);
    return (u + 0x7fffu + ((u >> 16) & 1u)) >> 16;
}
__device__ __forceinline__ unsigned int pk2(float lo, float hi) {
    return bf16_rne(lo) | (bf16_rne(hi) << 16);
}
__device__ __forceinline__ bf16x8 cvt8(float4 a, float4 b) {
    uint4 t = make_uint4(pk2(a.x, a.y), pk2(a.z, a.w), pk2(b.x, b.y), pk2(b.z, b.w));
    return __builtin_bit_cast(bf16x8, t);
}

// LDS: V^T [64 d][256 keys] bf16, slot' = slot ^ (d&7) ^ ((d>>3)&7)   (32KB)
//      P   [8 waves][16 q][40 k] bf16 per-wave scratch                (10KB)
// K is NOT staged: each wave streams its K tiles global->reg with depth-1
// prefetch (next tile's 8 float4 issued while current tile computes).
// Barrier covers only V -> half the staged bytes; K traffic overlaps compute.
__global__ __launch_bounds__(THREADS, 4)
void lattn_mfma(const float* __restrict__ Q, const float* __restrict__ K,
                const float* __restrict__ V, float* __restrict__ O) {
    __shared__ unsigned short Vs[DIM * KCAP];
    __shared__ unsigned short Ps[8 * 16 * 40];

    // bijective XCD swizzle: consecutive r0-blocks (overlapping halos) share an XCD L2
    const int nwg = gridDim.x;                 // 512
    const int cpx = nwg >> 3;
    const int bid = blockIdx.x;
    const int logical = (bid & 7) * cpx + (bid >> 3);
    const int bh = logical >> 5;               // 32 x-blocks per bh
    const int r0 = (logical & 31) * RB;

    const size_t base = (size_t)bh * (S_LEN * DIM);
    const float* Qg = Q + base;
    const float* Kg = K + base;
    const float* Vg = V + base;
    float*       Og = O + base;

    const int kstart = (r0 >= HALF) ? ((r0 - HALF) & ~31) : 0;
    const int kend   = min(S_LEN, r0 + RB + HALF);         // exclusive

    const int u = threadIdx.x;
    const int lane = u & 63;
    const int wv_  = u >> 6;
    const int g  = lane >> 4;
    const int cc = lane & 15;
    const int qlo = r0 + WQ * wv_;

    // ---- issue V loads (2 key-pair items/thread) and Q loads, then pack ----
    float4 vA[2][4];
    #pragma unroll
    for (int i = 0; i < 2; ++i) {
        const int idx = u + i * THREADS;
        const int kg  = kstart + (idx >> 3) * 2;
        const int d0  = (idx & 7) * 8;
        if (kg < kend) {                          // kend even -> pair never straddles
            const float* p = Vg + (size_t)kg * DIM + d0;
            vA[i][0] = *(const float4*)p;         vA[i][1] = *(const float4*)(p + 4);
            vA[i][2] = *(const float4*)(p + DIM); vA[i][3] = *(const float4*)(p + DIM + 4);
        } else {
            vA[i][0] = make_float4(0.f, 0.f, 0.f, 0.f);
            vA[i][1] = vA[i][0]; vA[i][2] = vA[i][0]; vA[i][3] = vA[i][0];
        }
    }
    float4 qA[2], qB[2];
    #pragma unroll
    for (int ds = 0; ds < 2; ++ds) {
        const float* src = Qg + (size_t)(qlo + cc) * DIM + ds * 32 + g * 8;
        qA[ds] = *(const float4*)src;
        qB[ds] = *(const float4*)(src + 4);
    }
    __builtin_amdgcn_sched_barrier(0);

    // ---- pack + write V^T (static j; swizzle spreads the 8 sharers across banks) ----
    #pragma unroll
    for (int i = 0; i < 2; ++i) {
        const int idx = u + i * THREADS;
        const int k0  = (idx >> 3) * 2;
        const int m   = idx & 7;
        const float* a0 = (const float*)&vA[i][0];   // key k0,   dims m*8..+8
        const float* a1 = (const float*)&vA[i][2];   // key k0+1
        #pragma unroll
        for (int j = 0; j < 8; ++j) {
            const int d  = m * 8 + j;
            const int sl = (k0 >> 3) ^ j ^ m;        // == (k0>>3)^(d&7)^((d>>3)&7)
            *(unsigned int*)(Vs + d * KCAP + sl * 8 + (k0 & 7)) = pk2(a0[j], a1[j]);
        }
    }
    // ---- pack Q fragments (scale folded) ----
    bf16x8 qf[2];
    #pragma unroll
    for (int ds = 0; ds < 2; ++ds) {
        float4 a = qA[ds], b = qB[ds];
        a.x*=SCALE; a.y*=SCALE; a.z*=SCALE; a.w*=SCALE;
        b.x*=SCALE; b.y*=SCALE; b.z*=SCALE; b.w*=SCALE;
        qf[ds] = cvt8(a, b);
    }

    __syncthreads();   // V^T staged (K never touches LDS)

    // ---- per-wave tile range ----
    int lo = (qlo >= HALF) ? (qlo - HALF) : 0;
    lo = max(kstart, lo & ~31);
    const int t0 = (lo - kstart) >> 5;
    const int hi = min(kend, qlo + WQ - 1 + HALF + 1);
    const int t1 = (hi - kstart + 31) >> 5;

    // K tile loader: 8 float4/lane = frags for one 32-key tile
    float4 kraw[8];
    auto k_issue = [&](int st) {
        const int kb32 = st << 5;
        #pragma unroll
        for (int kt = 0; kt < 2; ++kt) {
            const int krow = kstart + kb32 + kt * 16 + cc;
            if (krow < kend) {
                const float* p = Kg + (size_t)krow * DIM + g * 8;
                kraw[kt*4+0] = *(const float4*)p;        kraw[kt*4+1] = *(const float4*)(p + 4);
                kraw[kt*4+2] = *(const float4*)(p + 32); kraw[kt*4+3] = *(const float4*)(p + 36);
            } else {
                kraw[kt*4+0] = make_float4(0.f, 0.f, 0.f, 0.f);
                kraw[kt*4+1] = kraw[kt*4+0]; kraw[kt*4+2] = kraw[kt*4+0]; kraw[kt*4+3] = kraw[kt*4+0];
            }
        }
    };

    unsigned short* Pw = Ps + wv_ * (16 * 40);
    f32x4 oacc[4] = {};
    float denom = 0.f;

    k_issue(t0);   // prefetch first tile (flies while V pack of others settles)

    #pragma unroll
    for (int i = 0; i < NT; ++i) {
        const int st = t0 + i;
        if (st < t1) {
            const int kb32 = st << 5;

            // convert current tile (vmcnt-waits on kraw), then immediately
            // re-issue kraw for tile st+1 -> those loads fly under MFMA/softmax/PV
            bf16x8 ka[2][2];
            #pragma unroll
            for (int kt = 0; kt < 2; ++kt) {
                ka[0][kt] = cvt8(kraw[kt*4+0], kraw[kt*4+1]);
                ka[1][kt] = cvt8(kraw[kt*4+2], kraw[kt*4+3]);
            }
            if (st + 1 < t1) k_issue(st + 1);

            // swapped QK^T: S^T[key][q]
            f32x4 sacc[2] = {};
            #pragma unroll
            for (int ds = 0; ds < 2; ++ds) {
                #pragma unroll
                for (int kt = 0; kt < 2; ++kt)
                    sacc[kt] = __builtin_amdgcn_mfma_f32_16x16x32_bf16(ka[ds][kt], qf[ds], sacc[kt], 0, 0, 0);
            }

            // mask + exp + P layout shuffle (per-wave LDS, wave-internal sync only)
            const int q = qlo + cc;
            #pragma unroll
            for (int kt = 0; kt < 2; ++kt) {
                float w4[4];
                const int keyb = kstart + kb32 + kt * 16 + g * 4;
                #pragma unroll
                for (int r = 0; r < 4; ++r) {
                    const int key = keyb + r;
                    const float e = __expf(fminf(sacc[kt][r], 60.f));
                    const int dd  = key - q;
                    const bool ok = (dd >= -HALF) && (dd <= HALF) && (key < S_LEN);
                    w4[r] = ok ? e : 0.f;
                    denom += w4[r];
                }
                *(uint2*)(Pw + cc * 40 + kt * 16 + g * 4) =
                    make_uint2(pk2(w4[0], w4[1]), pk2(w4[2], w4[3]));
            }
            const bf16x8 pf = *(const bf16x8*)(Pw + cc * 40 + g * 8);

            // PV: O^T += V^T x P
            #pragma unroll
            for (int dt = 0; dt < 4; ++dt) {
                const int d  = dt * 16 + cc;
                const int sl = ((kb32 >> 3) + g) ^ (d & 7) ^ ((d >> 3) & 7);
                const bf16x8 vf = *(const bf16x8*)(Vs + d * KCAP + sl * 8);
                oacc[dt] = __builtin_amdgcn_mfma_f32_16x16x32_bf16(vf, pf, oacc[dt], 0, 0, 0);
            }
        }
    }

    // ---- normalize + store ----
    denom += __shfl_xor(denom, 16);
    denom += __shfl_xor(denom, 32);
    const float rinv = 1.f / denom;
    float* dst = Og + (size_t)(qlo + cc) * DIM;
    #pragma unroll
    for (int dt = 0; dt < 4; ++dt) {
        const f32x4 o = oacc[dt];
        *(float4*)(dst + dt * 16 + g * 4) =
            make_float4(o[0] * rinv, o[1] * rinv, o[2] * rinv, o[3] * rinv);
    }
}

extern "C" void kernel_launch(void* const* d_in, const int* in_sizes, int n_in,
                              void* d_out, int out_size, void* d_ws, size_t ws_size,
                              hipStream_t stream) {
    const float* q = (const float*)d_in[0];
    const float* k = (const float*)d_in[1];
    const float* v = (const float*)d_in[2];
    float* o = (float*)d_out;
    const int nbh = in_sizes[0] / (S_LEN * DIM);      // B*H = 16
    dim3 grid((S_LEN / RB) * nbh);                    // 512 blocks = 2/CU
    lattn_mfma<<<grid, THREADS, 0, stream>>>(q, k, v, o);
}

// Round 10
// 24.181 us; speedup vs baseline: 2.6504x; 2.6504x over previous
//
#include <hip/hip_runtime.h>

#define S_LEN 4096
#define DIM   64
#define HALF  50
#define RB    256           // query rows per block
#define WQ    16            // query rows per wave (16 waves)
#define THREADS 1024
#define KCAP  384           // staged keys: kstart = r0-64 (32-aligned), span <= 370
#define NT    5             // max 32-key tiles per wave (static unroll, reg P)
#define SCALE 0.125f

typedef __attribute__((ext_vector_type(8))) short bf16x8;
typedef __attribute__((ext_vector_type(4))) float f32x4;

__device__ __forceinline__ unsigned int bf16_rne(float f) {
    unsigned int u = __float_as_uint(f);
    return (u + 0x7fffu + ((u >> 16) & 1u)) >> 16;
}
__device__ __forceinline__ unsigned int pk2(float lo, float hi) {
    return bf16_rne(lo) | (bf16_rne(hi) << 16);
}
__device__ __forceinline__ bf16x8 cvt8(float4 a, float4 b) {
    uint4 t = make_uint4(pk2(a.x, a.y), pk2(a.z, a.w), pk2(b.x, b.y), pk2(b.z, b.w));
    return __builtin_bit_cast(bf16x8, t);
}

// LDS: K  [384 keys][64 d] bf16, slot' = slot ^ (key&7)                 (48KB)
//      V^T[64 d][384 keys] bf16, slot' = slot ^ (d&7) ^ ((d>>3)&7)      (48KB)
//      P  [16 waves][16 q][40 k] bf16 per-wave scratch                  (20KB)
// 3-phase split-barrier schedule: K pack waits only for K (V/Q stay in
// flight); barrier1; QK^T+softmax for ALL tiles with P in registers while
// V streams; V pack+write; barrier2; PV; store. HBM busy in every phase.
__global__ __launch_bounds__(THREADS, 4)
void lattn_mfma(const float* __restrict__ Q, const float* __restrict__ K,
                const float* __restrict__ V, float* __restrict__ O) {
    __shared__ unsigned short Ks[KCAP * 64];
    __shared__ unsigned short Vs[DIM * KCAP];
    __shared__ unsigned short Ps[16 * 16 * 40];

    // bijective XCD swizzle: consecutive r0-blocks (overlapping halos) share an XCD L2
    const int nwg = gridDim.x;                 // 256
    const int cpx = nwg >> 3;
    const int bid = blockIdx.x;
    const int logical = (bid & 7) * cpx + (bid >> 3);
    const int bh = logical >> 4;               // 16 x-blocks per bh
    const int r0 = (logical & 15) * RB;

    const size_t base = (size_t)bh * (S_LEN * DIM);
    const float* Qg = Q + base;
    const float* Kg = K + base;
    const float* Vg = V + base;
    float*       Og = O + base;

    const int kstart = (r0 >= HALF) ? ((r0 - HALF) & ~31) : 0;
    const int kend   = min(S_LEN, r0 + RB + HALF);         // exclusive

    const int u = threadIdx.x;
    const int lane = u & 63;
    const int wv_  = u >> 6;
    const int g  = lane >> 4;
    const int cc = lane & 15;
    const int qlo = r0 + WQ * wv_;

    // ============ phase 0: issue ALL loads (K first, then V, then Q) ============
    float4 kA[3], kB[3];      // K: rows (u>>3)+i*128, oct u&7
    #pragma unroll
    for (int i = 0; i < 3; ++i) {
        const int kg  = kstart + (u >> 3) + i * 128;
        const int oct = u & 7;
        if (kg < kend) {
            const float* p = Kg + (size_t)kg * DIM + oct * 8;
            kA[i] = *(const float4*)p; kB[i] = *(const float4*)(p + 4);
        } else {
            kA[i] = make_float4(0.f, 0.f, 0.f, 0.f); kB[i] = kA[i];
        }
    }
    float4 vA[2][4];          // V: key-pairs (u>>3)*2+i*256, d-octet u&7
    #pragma unroll
    for (int i = 0; i < 2; ++i) {
        if (i == 0 || u < 512) {
            const int kg = kstart + (u >> 3) * 2 + i * 256;
            const int d0 = (u & 7) * 8;
            if (kg < kend) {                  // kend even -> pair never straddles
                const float* p = Vg + (size_t)kg * DIM + d0;
                vA[i][0] = *(const float4*)p;         vA[i][1] = *(const float4*)(p + 4);
                vA[i][2] = *(const float4*)(p + DIM); vA[i][3] = *(const float4*)(p + DIM + 4);
            } else {
                vA[i][0] = make_float4(0.f, 0.f, 0.f, 0.f);
                vA[i][1] = vA[i][0]; vA[i][2] = vA[i][0]; vA[i][3] = vA[i][0];
            }
        }
    }
    float4 qA[2], qB[2];
    #pragma unroll
    for (int ds = 0; ds < 2; ++ds) {
        const float* src = Qg + (size_t)(qlo + cc) * DIM + ds * 32 + g * 8;
        qA[ds] = *(const float4*)src;
        qB[ds] = *(const float4*)(src + 4);
    }
    __builtin_amdgcn_sched_barrier(0);   // pin all load-issues above the packs

    // ---- pack + write K (vmcnt wait retires only K; V/Q stay in flight) ----
    #pragma unroll
    for (int i = 0; i < 3; ++i) {
        const int krow = (u >> 3) + i * 128;
        const int oct  = u & 7;
        *(uint4*)(Ks + krow * 64 + ((oct ^ (krow & 7)) << 3)) =
            __builtin_bit_cast(uint4, cvt8(kA[i], kB[i]));
    }
    // ---- pack Q fragments (scale folded) ----
    bf16x8 qf[2];
    #pragma unroll
    for (int ds = 0; ds < 2; ++ds) {
        float4 a = qA[ds], b = qB[ds];
        a.x*=SCALE; a.y*=SCALE; a.z*=SCALE; a.w*=SCALE;
        b.x*=SCALE; b.y*=SCALE; b.z*=SCALE; b.w*=SCALE;
        qf[ds] = cvt8(a, b);
    }

    __syncthreads();   // barrier 1: K staged (V still streaming)

    // ============ phase 1: QK^T + softmax for ALL tiles, P in registers ============
    int lo = (qlo >= HALF) ? (qlo - HALF) : 0;
    lo = max(kstart, lo & ~31);
    const int t0 = (lo - kstart) >> 5;
    const int hi = min(kend, qlo + WQ - 1 + HALF + 1);
    const int t1 = (hi - kstart + 31) >> 5;

    unsigned short* Pw = Ps + wv_ * (16 * 40);
    float denom = 0.f;
    bf16x8 pfr[NT];          // static-indexed (unrolled) -> registers

    #pragma unroll
    for (int i = 0; i < NT; ++i) {
        const int st = t0 + i;
        if (st < t1) {
            const int kb32 = st << 5;

            // swapped QK^T: S^T[key][q]
            f32x4 sacc[2] = {};
            #pragma unroll
            for (int ds = 0; ds < 2; ++ds) {
                #pragma unroll
                for (int kt = 0; kt < 2; ++kt) {
                    const int krow = kb32 + kt * 16 + cc;
                    const int sl   = (ds * 4 + g) ^ (krow & 7);
                    const bf16x8 kfr = *(const bf16x8*)(Ks + krow * 64 + sl * 8);
                    sacc[kt] = __builtin_amdgcn_mfma_f32_16x16x32_bf16(kfr, qf[ds], sacc[kt], 0, 0, 0);
                }
            }

            // mask + exp + P layout shuffle (per-wave LDS, wave-internal sync only)
            const int q = qlo + cc;
            #pragma unroll
            for (int kt = 0; kt < 2; ++kt) {
                float w4[4];
                const int keyb = kstart + kb32 + kt * 16 + g * 4;
                #pragma unroll
                for (int r = 0; r < 4; ++r) {
                    const int key = keyb + r;
                    const float e = __expf(fminf(sacc[kt][r], 60.f));
                    const int dd  = key - q;
                    const bool ok = (dd >= -HALF) && (dd <= HALF) && (key < S_LEN);
                    w4[r] = ok ? e : 0.f;
                    denom += w4[r];
                }
                *(uint2*)(Pw + cc * 40 + kt * 16 + g * 4) =
                    make_uint2(pk2(w4[0], w4[1]), pk2(w4[2], w4[3]));
            }
            pfr[i] = *(const bf16x8*)(Pw + cc * 40 + g * 8);
        }
    }

    // ============ phase 2: pack + write V^T (loads landed during phase 1) ============
    #pragma unroll
    for (int i = 0; i < 2; ++i) {
        if (i == 0 || u < 512) {
            const int k0 = (u >> 3) * 2 + i * 256;
            const int m  = u & 7;
            const float* a0 = (const float*)&vA[i][0];   // key k0,   dims m*8..+8
            const float* a1 = (const float*)&vA[i][2];   // key k0+1
            #pragma unroll
            for (int j = 0; j < 8; ++j) {
                const int d  = m * 8 + j;
                const int sl = (k0 >> 3) ^ j ^ m;        // == (k0>>3)^(d&7)^((d>>3)&7)
                *(unsigned int*)(Vs + d * KCAP + sl * 8 + (k0 & 7)) = pk2(a0[j], a1[j]);
            }
        }
    }

    __syncthreads();   // barrier 2: V^T staged

    // ============ phase 3: PV for all tiles + store ============
    f32x4 oacc[4] = {};
    #pragma unroll
    for (int i = 0; i < NT; ++i) {
        const int st = t0 + i;
        if (st < t1) {
            const int kb32 = st << 5;
            #pragma unroll
            for (int dt = 0; dt < 4; ++dt) {
                const int d  = dt * 16 + cc;
                const int sl = ((kb32 >> 3) + g) ^ (d & 7) ^ ((d >> 3) & 7);
                const bf16x8 vf = *(const bf16x8*)(Vs + d * KCAP + sl * 8);
                oacc[dt] = __builtin_amdgcn_mfma_f32_16x16x32_bf16(vf, pfr[i], oacc[dt], 0, 0, 0);
            }
        }
    }

    denom += __shfl_xor(denom, 16);
    denom += __shfl_xor(denom, 32);
    const float rinv = 1.f / denom;
    float* dst = Og + (size_t)(qlo + cc) * DIM;
    #pragma unroll
    for (int dt = 0; dt < 4; ++dt) {
        const f32x4 o = oacc[dt];
        *(float4*)(dst + dt * 16 + g * 4) =
            make_float4(o[0] * rinv, o[1] * rinv, o[2] * rinv, o[3] * rinv);
    }
}

extern "C" void kernel_launch(void* const* d_in, const int* in_sizes, int n_in,
                              void* d_out, int out_size, void* d_ws, size_t ws_size,
                              hipStream_t stream) {
    const float* q = (const float*)d_in[0];
    const float* k = (const float*)d_in[1];
    const float* v = (const float*)d_in[2];
    float* o = (float*)d_out;
    const int nbh = in_sizes[0] / (S_LEN * DIM);      // B*H = 16
    dim3 grid((S_LEN / RB) * nbh);                    // 256 blocks = 1/CU
    lattn_mfma<<<grid, THREADS, 0, stream>>>(q, k, v, o);
}